// Round 3
// baseline (22421.783 us; speedup 1.0000x reference)
//
#include <hip/hip_runtime.h>
#include <math.h>

#define B_   64
#define T_   256
#define OUTD 1216

typedef unsigned short ushort_t;
typedef unsigned int   uint32;
typedef __attribute__((ext_vector_type(8))) short bfrag;   // 8 bf16
typedef __attribute__((ext_vector_type(4))) float f32x4;
typedef __attribute__((ext_vector_type(4))) unsigned short us4;

__device__ __forceinline__ float sigmoidf_(float x) { return 1.0f / (1.0f + __expf(-x)); }
__device__ __forceinline__ float softplusf_(float x) { return (x > 20.0f) ? x : log1pf(__expf(x)); }
__device__ __forceinline__ ushort_t f2bf(float f) {
    uint32 u = __float_as_uint(f);
    u += 0x7fffu + ((u >> 16) & 1u);
    return (ushort_t)(u >> 16);
}
__device__ __forceinline__ float bf2f(ushort_t u) { return __uint_as_float(((uint32)u) << 16); }

// Device-scope barrier for 64 co-resident blocks. barf[0]/barf[32]: parity
// counters, barf[64]: release word. All zeroed by kwprep each launch (so the
// 0xAA ws poison never reaches the protocol). Generations are monotonic; the
// signed compare makes any residual garbage (negative) spin, never pass.
__device__ __forceinline__ void gbar(uint32* barf, int gen) {
    __syncthreads();
    if (threadIdx.x == 0) {
        __threadfence();
        uint32 old = __hip_atomic_fetch_add(barf + (gen & 1) * 32, 1u,
                                            __ATOMIC_ACQ_REL, __HIP_MEMORY_SCOPE_AGENT);
        if (old == 63u) {
            __hip_atomic_store(barf + (gen & 1) * 32, 0u, __ATOMIC_RELAXED, __HIP_MEMORY_SCOPE_AGENT);
            __hip_atomic_store(barf + 64, (uint32)gen, __ATOMIC_RELEASE, __HIP_MEMORY_SCOPE_AGENT);
        }
        while ((int)__hip_atomic_load(barf + 64, __ATOMIC_ACQUIRE, __HIP_MEMORY_SCOPE_AGENT) < gen)
            __builtin_amdgcn_s_sleep(1);
    }
    __syncthreads();
    __threadfence();
}

// ---------------------------------------------------------------------------
// kwprep: one-time weight conversion + barrier-flag zeroing.
// ---------------------------------------------------------------------------
__global__ void kwprep(const float* __restrict__ Wih, const float* __restrict__ Whh,
                       const float* __restrict__ Wp1, const float* __restrict__ Wq1,
                       const float* __restrict__ Wp2, const float* __restrict__ Wq2,
                       const float* __restrict__ Wsa,
                       ushort_t* Wih_b, ushort_t* Whh_b, ushort_t* Wp1_b, ushort_t* Wq1_b,
                       ushort_t* W2sw, ushort_t* Wsasw, uint32* barf) {
    int stride = gridDim.x * blockDim.x;
    int gid = blockIdx.x * blockDim.x + threadIdx.x;
    if (gid < 256) barf[gid] = 0u;
    for (int i = gid; i < 3072 * 1024; i += stride) Wih_b[i] = f2bf(Wih[i]);
    for (int i = gid; i < 3072 * 1024; i += stride) Whh_b[i] = f2bf(Whh[i]);
    for (int i = gid; i < 512 * 1024; i += stride) Wp1_b[i] = f2bf(Wp1[i]);
    for (int i = gid; i < 512 * 2048; i += stride) Wq1_b[i] = f2bf(Wq1[i]);
    for (int i = gid; i < 65536; i += stride) {
        int head = i >> 15, g = (i >> 9) & 63, o = (i >> 3) & 63, ii = i & 7;
        const float* src = head ? Wq2 : Wp2;
        W2sw[i] = f2bf(src[o * 512 + g * 8 + ii]);
    }
    for (int i = gid; i < 98304; i += stride) {
        int g = i >> 13, j = (i >> 3) & 1023, ii = i & 7;
        Wsasw[i] = f2bf(Wsa[j * 96 + g * 8 + ii]);
    }
}

// ---------------------------------------------------------------------------
// krollout: persistent kernel, 64 blocks x 256 threads, whole T=256 rollout.
// ---------------------------------------------------------------------------
__global__ __launch_bounds__(256, 1) void krollout(
        const ushort_t* Wih, const ushort_t* Whh,
        const float* bih, const float* bhh,
        const ushort_t* Wp1b, const float* bp1,
        const ushort_t* Wq1b, const float* bq1,
        const ushort_t* W2sw, const float* bp2, const float* bq2,
        const ushort_t* Wsasw, const float* Wsa, const float* bsa,
        const float* obs, const float* act,
        const float* n_p, const float* n_q,
        ushort_t* emb_sw, ushort_t* obs_sw,
        ushort_t* det_sw0, ushort_t* det_sw1,
        float* det_fp0, float* det_fp1,
        float* pm1, float* qm1,
        float* out, uint32* barf) {
    __shared__ float red[12288];   // 48 KB, shared by all phases
    const int bid = blockIdx.x, tid = threadIdx.x;
    const int lane = tid & 63, w = tid >> 6;
    const int m = lane & 15, quad = lane >> 4;

    // ---- pre-loop init: det(0)=0, emb(0) from act only (stoch0=0), obs_sw(0)
    *(f32x4*)(det_fp0 + bid * 1024 + tid * 4) = (f32x4){0.f, 0.f, 0.f, 0.f};
    *(us4*)(det_sw0 + bid * 1024 + tid * 4) = (us4){0, 0, 0, 0};
    {
        int j0i = bid * 16;
        for (int c4 = 0; c4 < 4; ++c4) {
            int idx = c4 * 256 + tid;
            int j = j0i + (idx >> 6), b2 = idx & 63;
            float acc = bsa[j];
            const float* a = act + (size_t)b2 * T_ * 64;
            const float* ww = Wsa + j * 96 + 32;
            for (int c = 0; c < 64; ++c) acc += a[c] * ww[c];
            emb_sw[((j >> 3) * 64 + b2) * 8 + (j & 7)] = f2bf(fmaxf(acc, 0.f));
        }
        float4 v = *(const float4*)(obs + (size_t)bid * T_ * 1024 + tid * 4);
        us4 o4; o4[0] = f2bf(v.x); o4[1] = f2bf(v.y); o4[2] = f2bf(v.z); o4[3] = f2bf(v.w);
        int k = tid * 4;
        *(us4*)(obs_sw + ((k >> 3) * 64 + bid) * 8 + (k & 7)) = o4;
    }
    int gen = 1;
    gbar(barf, gen); ++gen;

    for (int t = 0; t < T_; ++t) {
        ushort_t* dsw_in  = (t & 1) ? det_sw1 : det_sw0;
        ushort_t* dsw_out = (t & 1) ? det_sw0 : det_sw1;
        float* dfp_in  = (t & 1) ? det_fp1 : det_fp0;
        float* dfp_out = (t & 1) ? det_fp0 : det_fp1;

        // ================= phase A: GRU (j-span 16 per block) ==============
        {
            const int j0 = bid * 16;
            f32x4 acc[2][3][4];
#pragma unroll
            for (int a2 = 0; a2 < 2; ++a2)
#pragma unroll
                for (int g = 0; g < 3; ++g)
#pragma unroll
                    for (int n = 0; n < 4; ++n) acc[a2][g][n] = (f32x4){0.f, 0.f, 0.f, 0.f};

            const int kb0 = w * 256;
            const ushort_t* arow[2][3];
#pragma unroll
            for (int g = 0; g < 3; ++g) {
                arow[0][g] = Wih + (size_t)(g * 1024 + j0 + m) * 1024 + kb0 + quad * 8;
                arow[1][g] = Whh + (size_t)(g * 1024 + j0 + m) * 1024 + kb0 + quad * 8;
            }
            const ushort_t* bx = emb_sw + ((kb0 >> 3) + quad) * 512 + m * 8;
            const ushort_t* bh = dsw_in + ((kb0 >> 3) + quad) * 512 + m * 8;

#pragma unroll
            for (int it = 0; it < 8; ++it) {
                bfrag a[2][3], vx[4], vh[4];
#pragma unroll
                for (int g = 0; g < 3; ++g) {
                    a[0][g] = *(const bfrag*)(arow[0][g] + it * 32);
                    a[1][g] = *(const bfrag*)(arow[1][g] + it * 32);
                }
#pragma unroll
                for (int n = 0; n < 4; ++n) {
                    vx[n] = *(const bfrag*)(bx + it * 2048 + n * 128);
                    vh[n] = *(const bfrag*)(bh + it * 2048 + n * 128);
                }
#pragma unroll
                for (int g = 0; g < 3; ++g)
#pragma unroll
                    for (int n = 0; n < 4; ++n) {
                        acc[0][g][n] = __builtin_amdgcn_mfma_f32_16x16x32_bf16(a[0][g], vx[n], acc[0][g][n], 0, 0, 0);
                        acc[1][g][n] = __builtin_amdgcn_mfma_f32_16x16x32_bf16(a[1][g], vh[n], acc[1][g][n], 0, 0, 0);
                    }
            }
            if (w & 1) {
                float* dst = red + (w >> 1) * 6144;
#pragma unroll
                for (int a2 = 0; a2 < 2; ++a2)
#pragma unroll
                    for (int g = 0; g < 3; ++g)
#pragma unroll
                        for (int n = 0; n < 4; ++n)
                            *(f32x4*)(dst + ((a2 * 3 + g) * 4 + n) * 256 + lane * 4) = acc[a2][g][n];
            }
            __syncthreads();
            if (!(w & 1)) {
                float* dst = red + (w >> 1) * 6144;
#pragma unroll
                for (int a2 = 0; a2 < 2; ++a2)
#pragma unroll
                    for (int g = 0; g < 3; ++g)
#pragma unroll
                        for (int n = 0; n < 4; ++n) {
                            float* pp = dst + ((a2 * 3 + g) * 4 + n) * 256 + lane * 4;
                            f32x4 v = *(const f32x4*)pp;
                            v += acc[a2][g][n];
                            *(f32x4*)pp = v;
                        }
            }
            __syncthreads();
            int b = tid >> 2, jq = tid & 3;
            int nt = b >> 4, bl = b & 15;
            int lsrc = (jq * 16 + bl) * 4;
            float gg[2][3][4];
#pragma unroll
            for (int a2 = 0; a2 < 2; ++a2)
#pragma unroll
                for (int g = 0; g < 3; ++g) {
                    f32x4 v0 = *(const f32x4*)(red + ((a2 * 3 + g) * 4 + nt) * 256 + lsrc);
                    f32x4 v1 = *(const f32x4*)(red + 6144 + ((a2 * 3 + g) * 4 + nt) * 256 + lsrc);
#pragma unroll
                    for (int i = 0; i < 4; ++i) gg[a2][g][i] = v0[i] + v1[i];
                }
            f32x4 bi[3], bh2[3];
#pragma unroll
            for (int g = 0; g < 3; ++g) {
                bi[g] = *(const f32x4*)(bih + g * 1024 + j0 + jq * 4);
                bh2[g] = *(const f32x4*)(bhh + g * 1024 + j0 + jq * 4);
            }
            f32x4 h4;
            us4 dq;
#pragma unroll
            for (int i = 0; i < 4; ++i) {
                int j = j0 + jq * 4 + i;
                float r = sigmoidf_(gg[0][0][i] + bi[0][i] + gg[1][0][i] + bh2[0][i]);
                float z = sigmoidf_(gg[0][1][i] + bi[1][i] + gg[1][1][i] + bh2[1][i]);
                float n = tanhf(gg[0][2][i] + bi[2][i] + r * (gg[1][2][i] + bh2[2][i]));
                float hp = dfp_in[j * 64 + b];
                float h = (1.f - z) * n + z * hp;
                h4[i] = h;
                dq[i] = f2bf(h);
                dfp_out[j * 64 + b] = h;
            }
            *(f32x4*)(out + ((size_t)b * T_ + t) * OUTD + j0 + jq * 4) = h4;
            int kbase = j0 + jq * 4;
            *(us4*)(dsw_out + ((kbase >> 3) * 64 + b) * 8 + (kbase & 7)) = dq;
        }
        gbar(barf, gen); ++gen;

        // ================= phase B: pm1 (bid<32) / qm1 (bid>=32) ===========
        {
            const bool isq = bid >= 32;
            const int j0 = (isq ? bid - 32 : bid) * 16;
            f32x4 acc[4];
#pragma unroll
            for (int n = 0; n < 4; ++n) acc[n] = (f32x4){0.f, 0.f, 0.f, 0.f};

            if (!isq) {
                const ushort_t* ar = Wp1b + (size_t)(j0 + m) * 1024 + w * 256 + quad * 8;
                const ushort_t* bb = dsw_out + ((w * 32) + quad) * 512 + m * 8;
#pragma unroll
                for (int it = 0; it < 8; ++it) {
                    bfrag a = *(const bfrag*)(ar + it * 32);
#pragma unroll
                    for (int n = 0; n < 4; ++n) {
                        bfrag v = *(const bfrag*)(bb + it * 2048 + n * 128);
                        acc[n] = __builtin_amdgcn_mfma_f32_16x16x32_bf16(a, v, acc[n], 0, 0, 0);
                    }
                }
            } else {
                int kb0 = w * 512;
                const ushort_t* bsrc = (w < 2) ? dsw_out : obs_sw;
                int kloc = (w < 2) ? kb0 : kb0 - 1024;
                const ushort_t* ar = Wq1b + (size_t)(j0 + m) * 2048 + kb0 + quad * 8;
                const ushort_t* bb = bsrc + ((kloc >> 3) + quad) * 512 + m * 8;
#pragma unroll
                for (int it = 0; it < 16; ++it) {
                    bfrag a = *(const bfrag*)(ar + it * 32);
#pragma unroll
                    for (int n = 0; n < 4; ++n) {
                        bfrag v = *(const bfrag*)(bb + it * 2048 + n * 128);
                        acc[n] = __builtin_amdgcn_mfma_f32_16x16x32_bf16(a, v, acc[n], 0, 0, 0);
                    }
                }
            }
#pragma unroll
            for (int n = 0; n < 4; ++n)
                *(f32x4*)(red + (w * 4 + n) * 256 + lane * 4) = acc[n];
            __syncthreads();
            int b = tid >> 2, jq = tid & 3;
            int nt = b >> 4, lsrc = (jq * 16 + (b & 15)) * 4;
            f32x4 s = (f32x4){0.f, 0.f, 0.f, 0.f};
#pragma unroll
            for (int w2 = 0; w2 < 4; ++w2) s += *(const f32x4*)(red + (w2 * 4 + nt) * 256 + lsrc);
            f32x4 bv = *(const f32x4*)((isq ? bq1 : bp1) + j0 + jq * 4);
            f32x4 r;
#pragma unroll
            for (int i = 0; i < 4; ++i) r[i] = fmaxf(s[i] + bv[i], 0.f);
            *(f32x4*)((isq ? qm1 : pm1) + (size_t)b * 512 + j0 + jq * 4) = r;
        }
        gbar(barf, gen); ++gen;

        // ================= phase C: per-batch head + emb(t+1) + obs_sw(t+1)
        {
            float* s_p = red;
            float* s_q = red + 512;
            float* s_head = red + 1024;
            float* s_in = red + 1152;   // [0,32) stoch, [32,96) act(t+1)
            const int bb = bid;
            if (tid < 128) ((f32x4*)s_p)[tid] = ((const f32x4*)(pm1 + (size_t)bb * 512))[tid];
            else ((f32x4*)s_q)[tid - 128] = ((const f32x4*)(qm1 + (size_t)bb * 512))[tid - 128];
            if (t + 1 < T_ && tid < 64) s_in[32 + tid] = act[((size_t)bb * T_ + t + 1) * 64 + tid];
            __syncthreads();
            if (tid < 128) {
                int head = tid >> 6, o = tid & 63;
                const ushort_t* wp = W2sw + head * 32768 + o * 8;
                const float* hv = head ? s_q : s_p;
                float acc2 = (head ? bq2 : bp2)[o];
#pragma unroll 4
                for (int g = 0; g < 64; ++g) {
                    bfrag w8 = *(const bfrag*)(wp + g * 512);
#pragma unroll
                    for (int i2 = 0; i2 < 8; ++i2) acc2 += hv[g * 8 + i2] * bf2f((ushort_t)w8[i2]);
                }
                s_head[tid] = acc2;
            }
            __syncthreads();
            if (tid < 64) {
                int s = tid & 31, isq2 = tid >> 5;
                float mean = s_head[isq2 * 64 + s];
                float raw = s_head[isq2 * 64 + 32 + s];
                float sd = softplusf_(raw) + 1e-5f;
                float noise = (isq2 ? n_q : n_p)[((size_t)bb * T_ + t) * 32 + s];
                float st = mean + sd * noise;
                float* o = out + ((size_t)bb * T_ + t) * OUTD + 1024 + isq2 * 96;
                o[s] = mean;
                o[32 + s] = sd;
                o[64 + s] = st;
                if (isq2) s_in[s] = st;
            }
            __syncthreads();
            if (t + 1 < T_) {
#pragma unroll
                for (int q = 0; q < 4; ++q) {
                    int j = q * 256 + tid;
                    float acc2 = bsa[j];
#pragma unroll
                    for (int g = 0; g < 12; ++g) {
                        bfrag w8 = *(const bfrag*)(Wsasw + ((size_t)g * 1024 + j) * 8);
#pragma unroll
                        for (int i2 = 0; i2 < 8; ++i2) acc2 += s_in[g * 8 + i2] * bf2f((ushort_t)w8[i2]);
                    }
                    emb_sw[((j >> 3) * 64 + bb) * 8 + (j & 7)] = f2bf(fmaxf(acc2, 0.f));
                }
                float4 v = *(const float4*)(obs + ((size_t)bb * T_ + t + 1) * 1024 + tid * 4);
                us4 o4; o4[0] = f2bf(v.x); o4[1] = f2bf(v.y); o4[2] = f2bf(v.z); o4[3] = f2bf(v.w);
                int k = tid * 4;
                *(us4*)(obs_sw + ((k >> 3) * 64 + bb) * 8 + (k & 7)) = o4;
            }
        }
        if (t + 1 < T_) { gbar(barf, gen); ++gen; }
    }
}

extern "C" void kernel_launch(void* const* d_in, const int* in_sizes, int n_in,
                              void* d_out, int out_size, void* d_ws, size_t ws_size,
                              hipStream_t stream) {
    const float* obs = (const float*)d_in[0];
    const float* act = (const float*)d_in[1];
    const float* n_p = (const float*)d_in[2];
    const float* n_q = (const float*)d_in[3];
    const float* W_sa = (const float*)d_in[4];
    const float* b_sa = (const float*)d_in[5];
    const float* W_ih = (const float*)d_in[6];
    const float* b_ih = (const float*)d_in[7];
    const float* W_hh = (const float*)d_in[8];
    const float* b_hh = (const float*)d_in[9];
    const float* Wp1 = (const float*)d_in[10];
    const float* bp1 = (const float*)d_in[11];
    const float* Wp2 = (const float*)d_in[12];
    const float* bp2 = (const float*)d_in[13];
    const float* Wq1 = (const float*)d_in[14];
    const float* bq1 = (const float*)d_in[15];
    const float* Wq2 = (const float*)d_in[16];
    const float* bq2 = (const float*)d_in[17];
    float* out = (float*)d_out;

    char* p = (char*)d_ws;
    uint32* barf = (uint32*)p;       p += 256 * 4;
    ushort_t* Wih_b = (ushort_t*)p;  p += (size_t)3145728 * 2;
    ushort_t* Whh_b = (ushort_t*)p;  p += (size_t)3145728 * 2;
    ushort_t* Wp1_b = (ushort_t*)p;  p += (size_t)524288 * 2;
    ushort_t* Wq1_b = (ushort_t*)p;  p += (size_t)1048576 * 2;
    ushort_t* W2sw  = (ushort_t*)p;  p += (size_t)65536 * 2;
    ushort_t* Wsasw = (ushort_t*)p;  p += (size_t)98304 * 2;
    ushort_t* emb_sw = (ushort_t*)p; p += (size_t)65536 * 2;
    ushort_t* obs_sw = (ushort_t*)p; p += (size_t)65536 * 2;
    ushort_t* det_sw0 = (ushort_t*)p; p += (size_t)65536 * 2;
    ushort_t* det_sw1 = (ushort_t*)p; p += (size_t)65536 * 2;
    float* det_fp0 = (float*)p; p += (size_t)65536 * 4;
    float* det_fp1 = (float*)p; p += (size_t)65536 * 4;
    float* pm1 = (float*)p; p += (size_t)32768 * 4;
    float* qm1 = (float*)p; p += (size_t)32768 * 4;

    kwprep<<<1024, 256, 0, stream>>>(W_ih, W_hh, Wp1, Wq1, Wp2, Wq2, W_sa,
                                     Wih_b, Whh_b, Wp1_b, Wq1_b, W2sw, Wsasw, barf);
    krollout<<<64, 256, 0, stream>>>(Wih_b, Whh_b, b_ih, b_hh, Wp1_b, bp1, Wq1_b, bq1,
                                     W2sw, bp2, bq2, Wsasw, W_sa, b_sa,
                                     obs, act, n_p, n_q,
                                     emb_sw, obs_sw, det_sw0, det_sw1,
                                     det_fp0, det_fp1, pm1, qm1, out, barf);
}